// Round 9
// baseline (94.872 us; speedup 1.0000x reference)
//
#include <hip/hip_runtime.h>
#include <hip/hip_bf16.h>
#include <math.h>

// Sizes (fixed by the problem)
#define B 8
#define MEM_LEN 512
#define DEC_LEN 32
#define HDIM 1024
#define M1 513
#define PM_ROWS (B * M1)   // 4104
#define AROWS 4224         // 66*64 padded pm rows

// Finite -inf stand-in (exact -inf makes |ref-out| = NaN in the harness check).
#define NEG_BIG (-1e30f)
// 2*log2(e): tanh(x) = 1 - 2*rcp(1 + exp2(C2*x)). Folded into W at convert
// time (wmb = C2*W) and into the bias at the GEMM epilogue.
#define C2F 2.885390081777927f

#if __has_builtin(__builtin_amdgcn_exp2f)
#define EXP2(x) __builtin_amdgcn_exp2f(x)
#else
#define EXP2(x) exp2f(x)
#endif
#define RCP(x) __builtin_amdgcn_rcpf(x)
#define SCHED_FENCE() __builtin_amdgcn_sched_barrier(0)

typedef __bf16 bfv8 __attribute__((ext_vector_type(8)));
typedef float  f4   __attribute__((ext_vector_type(4)));
typedef float  f8   __attribute__((ext_vector_type(8)));

// ---------------------------------------------------------------------------
// Kernel 1: convert GEMM operands to bf16 (assemble mem_full + zero pad;
// weights pre-scaled by C2). One thread = 8 elements.
// ---------------------------------------------------------------------------
#define N_MF  (AROWS * 512 / 8)         // 270336
#define N_DEC (256 * 512 / 8)           // 16384
#define N_W   (1024 * 512 / 8)          // 65536
#define N_CVT (N_MF + N_DEC + 2 * N_W)  // 417792 = 1632*256

__global__ __launch_bounds__(256) void convert_all(
        const float* __restrict__ mem, const float* __restrict__ term,
        const float* __restrict__ dec_hid,
        const float* __restrict__ W_mem, const float* __restrict__ W_dec,
        __bf16* __restrict__ mfb, __bf16* __restrict__ decb,
        __bf16* __restrict__ wmb, __bf16* __restrict__ wdb) {
    int idx = blockIdx.x * 256 + threadIdx.x;
    float4 v0 = make_float4(0.f, 0.f, 0.f, 0.f), v1 = v0;
    float scale = 1.f;
    __bf16* dst;
    if (idx < N_MF) {
        int row = idx >> 6;          // 64 chunks of 8 per 512-wide row
        int c8  = idx & 63;
        dst = mfb + (size_t)idx * 8;
        if (row < PM_ROWS) {
            int b = row / M1, m = row - b * M1;
            const float* src = (m == 0) ? (term + c8 * 8)
                                        : (mem + ((size_t)(b * MEM_LEN + m - 1)) * 512 + c8 * 8);
            v0 = ((const float4*)src)[0];
            v1 = ((const float4*)src)[1];
        } // else rows >= 4104 stay zero (GEMM pad)
    } else if (idx < N_MF + N_DEC) {
        int j = idx - N_MF;
        dst = decb + (size_t)j * 8;
        v0 = ((const float4*)dec_hid)[j * 2];
        v1 = ((const float4*)dec_hid)[j * 2 + 1];
    } else if (idx < N_MF + N_DEC + N_W) {
        int j = idx - N_MF - N_DEC;
        dst = wmb + (size_t)j * 8;
        v0 = ((const float4*)W_mem)[j * 2];
        v1 = ((const float4*)W_mem)[j * 2 + 1];
        scale = C2F;
    } else {
        int j = idx - N_MF - N_DEC - N_W;
        dst = wdb + (size_t)j * 8;
        v0 = ((const float4*)W_dec)[j * 2];
        v1 = ((const float4*)W_dec)[j * 2 + 1];
        scale = C2F;
    }
    bfv8 o;
    o[0] = (__bf16)(v0.x * scale); o[1] = (__bf16)(v0.y * scale);
    o[2] = (__bf16)(v0.z * scale); o[3] = (__bf16)(v0.w * scale);
    o[4] = (__bf16)(v1.x * scale); o[5] = (__bf16)(v1.y * scale);
    o[6] = (__bf16)(v1.z * scale); o[7] = (__bf16)(v1.w * scale);
    *(bfv8*)dst = o;
}

// ---------------------------------------------------------------------------
// Kernel 2: bf16 MFMA GEMM, direct-from-global fragments with an EXPLICIT
// depth-2 register pipeline: step k+1's 4 loads are issued into named regs,
// then sched_barrier(0), then step k's MFMAs. The compiler then emits a
// counted vmcnt(4) (not a drain), keeping ~8 loads in flight per wave.
// R8 evidence: without this the backend compiles to 36 VGPR and serializes
// every load (40 us, MfmaUtil 3.8%).
// Chunked-bijective XCD swizzle (1120 = 8*140) keeps each A-panel's 16
// by-blocks on one XCD's L2 (R6: 34MB refetch without it; R8: FETCH=7MB).
// Layouts (HW-verified m89/m91): A/B frag lane l -> row (l&15), k=(l>>4)*8+j;
// C/D: col = l&15, row = (l>>4)*4 + reg.
// ---------------------------------------------------------------------------
__global__ __launch_bounds__(256, 4) void gemm_mfma2f(
        const __bf16* __restrict__ mfb, const __bf16* __restrict__ decb,
        const __bf16* __restrict__ wmb, const __bf16* __restrict__ wdb,
        const float* __restrict__ b_mem, const float* __restrict__ b_dec,
        __bf16* __restrict__ pmb, __bf16* __restrict__ pdb) {
    int orig = blockIdx.x;                 // 0..1119
    int wg   = (orig & 7) * 140 + (orig >> 3);   // chunked XCD swizzle
    int bx   = wg >> 4;                    // 0..69
    int by   = wg & 15;

    bool isMem = bx < 66;
    const __bf16* A  = isMem ? mfb : decb;
    const __bf16* Wb = isMem ? wmb : wdb;
    const float* bsel = isMem ? b_mem : b_dec;
    __bf16* Cout      = isMem ? pmb : pdb;
    int rowBase = isMem ? bx * 64 : (bx - 66) * 64;

    int w = threadIdx.x >> 6, l = threadIdx.x & 63;
    int m0 = rowBase + (w >> 1) * 32;
    int n0 = by * 64 + (w & 1) * 32;
    int lr = l & 15;
    int lk = (l >> 4) * 8;
    const __bf16* Ab0 = A  + (size_t)(m0 + lr) * 512 + lk;
    const __bf16* Ab1 = Ab0 + 16 * 512;
    const __bf16* Bb0 = Wb + (size_t)(n0 + lr) * 512 + lk;
    const __bf16* Bb1 = Bb0 + 16 * 512;

    f4 acc[2][2] = {};
    // prologue: step-0 loads
    bfv8 ca0 = *(const bfv8*)(Ab0);
    bfv8 ca1 = *(const bfv8*)(Ab1);
    bfv8 cb0 = *(const bfv8*)(Bb0);
    bfv8 cb1 = *(const bfv8*)(Bb1);
    #pragma unroll
    for (int s = 0; s < 16; ++s) {
        bfv8 na0, na1, nb0, nb1;
        if (s < 15) {                     // compile-time folded (full unroll)
            int kn = (s + 1) * 32;
            na0 = *(const bfv8*)(Ab0 + kn);
            na1 = *(const bfv8*)(Ab1 + kn);
            nb0 = *(const bfv8*)(Bb0 + kn);
            nb1 = *(const bfv8*)(Bb1 + kn);
        }
        SCHED_FENCE();                    // loads stay above the MFMAs
        acc[0][0] = __builtin_amdgcn_mfma_f32_16x16x32_bf16(ca0, cb0, acc[0][0], 0, 0, 0);
        acc[0][1] = __builtin_amdgcn_mfma_f32_16x16x32_bf16(ca0, cb1, acc[0][1], 0, 0, 0);
        acc[1][0] = __builtin_amdgcn_mfma_f32_16x16x32_bf16(ca1, cb0, acc[1][0], 0, 0, 0);
        acc[1][1] = __builtin_amdgcn_mfma_f32_16x16x32_bf16(ca1, cb1, acc[1][1], 0, 0, 0);
        SCHED_FENCE();
        ca0 = na0; ca1 = na1; cb0 = nb0; cb1 = nb1;
    }

    int crow = (l >> 4) * 4;
    int ccol = l & 15;
    #pragma unroll
    for (int j = 0; j < 2; ++j) {
        int col = n0 + j * 16 + ccol;
        float bv = bsel[col] * C2F;
        #pragma unroll
        for (int i = 0; i < 2; ++i) {
            #pragma unroll
            for (int r = 0; r < 4; ++r) {
                int row = m0 + i * 16 + crow + r;
                Cout[(size_t)row * HDIM + col] = (__bf16)(acc[i][j][r] + bv);
            }
        }
    }
}

// ---------------------------------------------------------------------------
// Kernel 3: score[b,d,m] = SumW - sum_h 2*w[h]*rcp(1 + exp2(pm_s + pd_s))
// pm_s, pd_s pre-scaled by C2 (bf16). Grid: b(8) x dgroup(8, 4 d) x mchunk(17).
// b = bid&7 -> XCD (pm[b] slice L2-resident). Block 256 = 4 waves; wave w rows
// mbase..+7; lane covers 16 h. Depth-2 row pipeline: next row's pm loads are
// issued before this row's 64-element compute (sched_barrier separated), so
// the L2 latency hides under the tanh block. Branchless masks (cndmask).
// launch_bounds(256,4): VGPR cap 128 so pdv[4][2] stays register-resident
// (R8: default bounds -> 36 VGPR -> pdv re-loaded every row).
// ---------------------------------------------------------------------------
__global__ __launch_bounds__(256, 4) void score4(
        const __bf16* __restrict__ pm, const __bf16* __restrict__ pdb,
        const float* __restrict__ w_score,
        const unsigned char* __restrict__ mem_mask,
        const unsigned char* __restrict__ dec_mask,
        const unsigned char* __restrict__ dup_mask,
        float* __restrict__ sc) {
    int bid = blockIdx.x;
    int b    = bid & 7;
    int rest = bid >> 3;
    int dg   = rest & 7;
    int mc   = rest >> 3;                  // 0..16
    int t = threadIdx.x, w = t >> 6, l = t & 63;
    int bd0 = b * DEC_LEN + dg * 4;

    f8 pdv[4][2], w22[2];
    float sumw_l = 0.f;
    #pragma unroll
    for (int half = 0; half < 2; ++half) {
        int h = half * 512 + l * 8;
        f8 wv = *(const f8*)(w_score + h);
        #pragma unroll
        for (int d = 0; d < 4; ++d) {
            bfv8 pv = *(const bfv8*)(pdb + (size_t)(bd0 + d) * HDIM + h);
            #pragma unroll
            for (int j = 0; j < 8; ++j) pdv[d][half][j] = (float)pv[j];
        }
        #pragma unroll
        for (int j = 0; j < 8; ++j) {
            sumw_l += wv[j];
            w22[half][j] = wv[j] * 2.f;
        }
    }
    #pragma unroll
    for (int off = 32; off; off >>= 1) sumw_l += __shfl_xor(sumw_l, off, 64);
    float sumw_all = sumw_l;

    bool dm[4];
    #pragma unroll
    for (int d = 0; d < 4; ++d) dm[d] = dec_mask[bd0 + d] != 0;
    const unsigned char* dup0 = dup_mask + (size_t)bd0 * M1;

    int mbase = mc * 32 + w * 8;           // all 8 rows < 513 by construction? 
    // mc=16 -> mbase up to 16*32+3*8=536? No: mc*32 + w*8, mc<=16, w<=3 ->
    // 512+24+7 = 543 > 512. Guard rows >= M1 by clamping to row 0 (computed
    // but discarded on store).
    int rowm[8];
    bool rvalid[8];
    unsigned char mm[8];
    #pragma unroll
    for (int i = 0; i < 8; ++i) {
        int m = mbase + i;
        rvalid[i] = (m < M1);
        rowm[i] = rvalid[i] ? m : 0;
        mm[i] = (rowm[i] > 0) ? mem_mask[b * MEM_LEN + rowm[i] - 1] : (unsigned char)0;
    }

    const __bf16* pmbase = pm + (size_t)(b * M1) * HDIM + l * 8;
    // prologue: row 0 loads
    bfv8 p0c = *(const bfv8*)(pmbase + (size_t)rowm[0] * HDIM);
    bfv8 p1c = *(const bfv8*)(pmbase + (size_t)rowm[0] * HDIM + 512);

    #pragma unroll
    for (int i = 0; i < 8; ++i) {
        bfv8 p0n, p1n;
        if (i < 7) {
            p0n = *(const bfv8*)(pmbase + (size_t)rowm[i + 1] * HDIM);
            p1n = *(const bfv8*)(pmbase + (size_t)rowm[i + 1] * HDIM + 512);
        }
        SCHED_FENCE();                     // next-row loads stay above compute
        float ac[4][2] = {};
        #pragma unroll
        for (int j = 0; j < 8; ++j) {
            float pf = (float)p0c[j];
            float pg = (float)p1c[j];
            #pragma unroll
            for (int d = 0; d < 4; ++d) {
                float e0 = EXP2(pf + pdv[d][0][j]);
                ac[d][0] = fmaf(w22[0][j], RCP(e0 + 1.f), ac[d][0]);
                float e1 = EXP2(pg + pdv[d][1][j]);
                ac[d][1] = fmaf(w22[1][j], RCP(e1 + 1.f), ac[d][1]);
            }
        }
        float a0 = ac[0][0] + ac[0][1];
        float a1 = ac[1][0] + ac[1][1];
        float a2 = ac[2][0] + ac[2][1];
        float a3 = ac[3][0] + ac[3][1];
        #pragma unroll
        for (int off = 32; off; off >>= 1) {
            a0 += __shfl_xor(a0, off, 64);
            a1 += __shfl_xor(a1, off, 64);
            a2 += __shfl_xor(a2, off, 64);
            a3 += __shfl_xor(a3, off, 64);
        }
        int m = rowm[i];
        bool memm = mm[i] != 0;
        float s[4];
        s[0] = sumw_all - a0;
        s[1] = sumw_all - a1;
        s[2] = sumw_all - a2;
        s[3] = sumw_all - a3;
        #pragma unroll
        for (int d = 0; d < 4; ++d) {
            bool kill = memm || (!dm[d] && dup0[(size_t)d * M1 + m]);
            s[d] = kill ? NEG_BIG : s[d];
        }
        if (l == 0 && rvalid[i]) {
            #pragma unroll
            for (int d = 0; d < 4; ++d)
                sc[(size_t)(bd0 + d) * M1 + m] = s[d];
        }
        p0c = p0n; p1c = p1n;
    }
}

// ---------------------------------------------------------------------------
// Kernel 4: row-wise log_softmax over 513 entries. One block per (b,d).
// ---------------------------------------------------------------------------
__global__ __launch_bounds__(512) void softmax_k(const float* __restrict__ sc,
                                                 float* __restrict__ out) {
    __shared__ float red[512];
    int bd = blockIdx.x, t = threadIdx.x;
    const float* row = sc + (size_t)bd * M1;
    float v = row[t];
    float v512 = row[512];
    float lm = (t == 0) ? fmaxf(v, v512) : v;
    red[t] = lm;
    __syncthreads();
    for (int s = 256; s > 0; s >>= 1) {
        if (t < s) red[t] = fmaxf(red[t], red[t + s]);
        __syncthreads();
    }
    float mx = red[0];
    __syncthreads();
    float le = __expf(v - mx);             // exp(NEG_BIG - mx) == 0 exactly
    if (t == 0) le += __expf(v512 - mx);
    red[t] = le;
    __syncthreads();
    for (int s = 256; s > 0; s >>= 1) {
        if (t < s) red[t] += red[t + s];
        __syncthreads();
    }
    float lse = mx + __logf(red[0]);
    float* orow = out + (size_t)bd * M1;
    orow[t] = v - lse;
    if (t == 0) orow[512] = v512 - lse;
}

// ---------------------------------------------------------------------------
extern "C" void kernel_launch(void* const* d_in, const int* in_sizes, int n_in,
                              void* d_out, int out_size, void* d_ws, size_t ws_size,
                              hipStream_t stream) {
    const float* mem      = (const float*)d_in[0];
    const float* dec_hid  = (const float*)d_in[1];
    const unsigned char* mem_mask = (const unsigned char*)d_in[2];
    const unsigned char* dec_mask = (const unsigned char*)d_in[3];
    const unsigned char* dup_mask = (const unsigned char*)d_in[4];
    const float* term     = (const float*)d_in[5];
    const float* W_mem    = (const float*)d_in[6];
    const float* b_mem    = (const float*)d_in[7];
    const float* W_dec    = (const float*)d_in[8];
    const float* b_dec    = (const float*)d_in[9];
    const float* w_score  = (const float*)d_in[10];
    // d_in[11] = b_score : unused (log_softmax is shift-invariant)

    float* out = (float*)d_out;
    char* ws = (char*)d_ws;
    __bf16* mfb  = (__bf16*)ws;                              // 4224*512*2  = 4,325,376
    __bf16* decb = mfb + (size_t)AROWS * 512;                //  256*512*2  =   262,144
    __bf16* wmb  = decb + (size_t)256 * 512;                 // 1024*512*2  = 1,048,576
    __bf16* wdb  = wmb + (size_t)1024 * 512;                 // 1024*512*2  = 1,048,576
    __bf16* pmb  = wdb + (size_t)1024 * 512;                 // 4224*1024*2 = 8,650,752
    __bf16* pdb  = pmb + (size_t)AROWS * HDIM;               //  256*1024*2 =   524,288
    float*  sc   = (float*)(pdb + (size_t)256 * HDIM);       //  256*513*4  =   525,312

    convert_all<<<N_CVT / 256, 256, 0, stream>>>(mem, term, dec_hid, W_mem, W_dec,
                                                 mfb, decb, wmb, wdb);
    gemm_mfma2f<<<1120, 256, 0, stream>>>(mfb, decb, wmb, wdb, b_mem, b_dec, pmb, pdb);
    score4<<<8 * 8 * 17, 256, 0, stream>>>(pmb, pdb, w_score,
                                           mem_mask, dec_mask, dup_mask, sc);
    softmax_k<<<B * DEC_LEN, 512, 0, stream>>>(sc, out);
}

// Round 10
// 89.930 us; speedup vs baseline: 1.0549x; 1.0549x over previous
//
#include <hip/hip_runtime.h>
#include <hip/hip_bf16.h>
#include <math.h>

// Sizes (fixed by the problem)
#define B 8
#define MEM_LEN 512
#define DEC_LEN 32
#define HDIM 1024
#define M1 513
#define PM_ROWS (B * M1)   // 4104
#define AROWS 4224         // 66*64 padded pm rows

// Finite -inf stand-in (exact -inf makes |ref-out| = NaN in the harness check).
#define NEG_BIG (-1e30f)
// 2*log2(e): tanh(x) = 1 - 2*rcp(1 + exp2(C2*x)). Folded into W at convert
// time (wmb = C2*W) and into the bias at the GEMM epilogue.
#define C2F 2.885390081777927f

#if __has_builtin(__builtin_amdgcn_exp2f)
#define EXP2(x) __builtin_amdgcn_exp2f(x)
#else
#define EXP2(x) exp2f(x)
#endif
#define RCP(x) __builtin_amdgcn_rcpf(x)
#define SCHED_FENCE() __builtin_amdgcn_sched_barrier(0)

typedef __bf16 bfv8 __attribute__((ext_vector_type(8)));
typedef float  f4   __attribute__((ext_vector_type(4)));
typedef float  f8   __attribute__((ext_vector_type(8)));

// ---------------------------------------------------------------------------
// Kernel 1: convert GEMM operands to bf16 (assemble mem_full + zero pad;
// weights pre-scaled by C2). One thread = 8 elements.
// ---------------------------------------------------------------------------
#define N_MF  (AROWS * 512 / 8)         // 270336
#define N_DEC (256 * 512 / 8)           // 16384
#define N_W   (1024 * 512 / 8)          // 65536
#define N_CVT (N_MF + N_DEC + 2 * N_W)  // 417792 = 1632*256

__global__ __launch_bounds__(256) void convert_all(
        const float* __restrict__ mem, const float* __restrict__ term,
        const float* __restrict__ dec_hid,
        const float* __restrict__ W_mem, const float* __restrict__ W_dec,
        __bf16* __restrict__ mfb, __bf16* __restrict__ decb,
        __bf16* __restrict__ wmb, __bf16* __restrict__ wdb) {
    int idx = blockIdx.x * 256 + threadIdx.x;
    float4 v0 = make_float4(0.f, 0.f, 0.f, 0.f), v1 = v0;
    float scale = 1.f;
    __bf16* dst;
    if (idx < N_MF) {
        int row = idx >> 6;          // 64 chunks of 8 per 512-wide row
        int c8  = idx & 63;
        dst = mfb + (size_t)idx * 8;
        if (row < PM_ROWS) {
            int b = row / M1, m = row - b * M1;
            const float* src = (m == 0) ? (term + c8 * 8)
                                        : (mem + ((size_t)(b * MEM_LEN + m - 1)) * 512 + c8 * 8);
            v0 = ((const float4*)src)[0];
            v1 = ((const float4*)src)[1];
        } // else rows >= 4104 stay zero (GEMM pad)
    } else if (idx < N_MF + N_DEC) {
        int j = idx - N_MF;
        dst = decb + (size_t)j * 8;
        v0 = ((const float4*)dec_hid)[j * 2];
        v1 = ((const float4*)dec_hid)[j * 2 + 1];
    } else if (idx < N_MF + N_DEC + N_W) {
        int j = idx - N_MF - N_DEC;
        dst = wmb + (size_t)j * 8;
        v0 = ((const float4*)W_mem)[j * 2];
        v1 = ((const float4*)W_mem)[j * 2 + 1];
        scale = C2F;
    } else {
        int j = idx - N_MF - N_DEC - N_W;
        dst = wdb + (size_t)j * 8;
        v0 = ((const float4*)W_dec)[j * 2];
        v1 = ((const float4*)W_dec)[j * 2 + 1];
        scale = C2F;
    }
    bfv8 o;
    o[0] = (__bf16)(v0.x * scale); o[1] = (__bf16)(v0.y * scale);
    o[2] = (__bf16)(v0.z * scale); o[3] = (__bf16)(v0.w * scale);
    o[4] = (__bf16)(v1.x * scale); o[5] = (__bf16)(v1.y * scale);
    o[6] = (__bf16)(v1.z * scale); o[7] = (__bf16)(v1.w * scale);
    *(bfv8*)dst = o;
}

// ---------------------------------------------------------------------------
// Kernel 2: bf16 MFMA GEMM with a DEPTH-6 static register pipeline.
// R9 diagnosis: per k-step compute is only ~40cyc vs ~250-400cyc load
// latency, so depth-2 hid nothing; and without issue-order pinning the SSA
// scheduler always collapses to serial load->wait->MFMA (the invariant 40us).
// Here: 6-slot rotating bfv8 arrays (ALL indices compile-time -> registers),
// sched_barrier(0) pins per-step issue order {4 MFMA | 4 refill loads}.
// Steady state: 24 loads in flight, waitcnt = counted vmcnt(20), never 0.
// launch_bounds(256,3): VGPR cap ~168 so 24 staging bfv8 (96 regs) stay live.
// Chunked-bijective XCD swizzle (1120 = 8*140): A-panel's 16 by-blocks on one
// XCD L2 (R8: FETCH 7MB, minimal).
// Layouts (HW-verified m89/m91): A/B frag lane l -> row (l&15), k=(l>>4)*8+j;
// C/D: col = l&15, row = (l>>4)*4 + reg.
// ---------------------------------------------------------------------------
__global__ __launch_bounds__(256, 3) void gemm_pipe(
        const __bf16* __restrict__ mfb, const __bf16* __restrict__ decb,
        const __bf16* __restrict__ wmb, const __bf16* __restrict__ wdb,
        const float* __restrict__ b_mem, const float* __restrict__ b_dec,
        __bf16* __restrict__ pmb, __bf16* __restrict__ pdb) {
    int orig = blockIdx.x;                 // 0..1119
    int wg   = (orig & 7) * 140 + (orig >> 3);   // chunked XCD swizzle
    int bx   = wg >> 4;                    // 0..69
    int by   = wg & 15;

    bool isMem = bx < 66;
    const __bf16* A  = isMem ? mfb : decb;
    const __bf16* Wb = isMem ? wmb : wdb;
    const float* bsel = isMem ? b_mem : b_dec;
    __bf16* Cout      = isMem ? pmb : pdb;
    int rowBase = isMem ? bx * 64 : (bx - 66) * 64;

    int w = threadIdx.x >> 6, l = threadIdx.x & 63;
    int m0 = rowBase + (w >> 1) * 32;
    int n0 = by * 64 + (w & 1) * 32;
    int lr = l & 15;
    int lk = (l >> 4) * 8;
    const __bf16* Ab0 = A  + (size_t)(m0 + lr) * 512 + lk;
    const __bf16* Ab1 = Ab0 + 16 * 512;
    const __bf16* Bb0 = Wb + (size_t)(n0 + lr) * 512 + lk;
    const __bf16* Bb1 = Bb0 + 16 * 512;

    f4 acc[2][2] = {};
    bfv8 sa0[6], sa1[6], sb0[6], sb1[6];   // static-indexed only (rule #20)
    #pragma unroll
    for (int p = 0; p < 6; ++p) {          // prologue: 24 loads in flight
        sa0[p] = *(const bfv8*)(Ab0 + p * 32);
        sa1[p] = *(const bfv8*)(Ab1 + p * 32);
        sb0[p] = *(const bfv8*)(Bb0 + p * 32);
        sb1[p] = *(const bfv8*)(Bb1 + p * 32);
    }
    #pragma unroll
    for (int s = 0; s < 16; ++s) {
        const int sl = s % 6;              // literal under full unroll
        SCHED_FENCE();                     // pin: MFMAs of step s first
        acc[0][0] = __builtin_amdgcn_mfma_f32_16x16x32_bf16(sa0[sl], sb0[sl], acc[0][0], 0, 0, 0);
        acc[0][1] = __builtin_amdgcn_mfma_f32_16x16x32_bf16(sa0[sl], sb1[sl], acc[0][1], 0, 0, 0);
        acc[1][0] = __builtin_amdgcn_mfma_f32_16x16x32_bf16(sa1[sl], sb0[sl], acc[1][0], 0, 0, 0);
        acc[1][1] = __builtin_amdgcn_mfma_f32_16x16x32_bf16(sa1[sl], sb1[sl], acc[1][1], 0, 0, 0);
        SCHED_FENCE();                     // then refill slot with step s+6
        if (s + 6 < 16) {
            const int kn = (s + 6) * 32;
            sa0[sl] = *(const bfv8*)(Ab0 + kn);
            sa1[sl] = *(const bfv8*)(Ab1 + kn);
            sb0[sl] = *(const bfv8*)(Bb0 + kn);
            sb1[sl] = *(const bfv8*)(Bb1 + kn);
        }
    }

    int crow = (l >> 4) * 4;
    int ccol = l & 15;
    #pragma unroll
    for (int j = 0; j < 2; ++j) {
        int col = n0 + j * 16 + ccol;
        float bv = bsel[col] * C2F;
        #pragma unroll
        for (int i = 0; i < 2; ++i) {
            #pragma unroll
            for (int r = 0; r < 4; ++r) {
                int row = m0 + i * 16 + crow + r;
                Cout[(size_t)row * HDIM + col] = (__bf16)(acc[i][j][r] + bv);
            }
        }
    }
}

// ---------------------------------------------------------------------------
// Kernel 3: score[b,d,m] = SumW - sum_h 2*w[h]*rcp(1 + exp2(pm_s + pd_s))
// R9 diagnosis: pdv[4][2] f32 = 64 VGPRs; compiler (pressure-min) refused to
// hold it (VGPR_Count=64 total) and re-materialized pd loads every row ->
// 46.9us. Fix: pd tile lives in LDS (4x1024 bf16 = 8KB, staged once per
// block); per row 8 explicit conflict-free ds_read_b128 (+~6% over ideal) —
// LDS reads can't be spilled away, so perf is allocator-independent.
// Grid: b(8) x dgroup(8, 4 d) x mchunk(17). b = bid&7 -> XCD. Wave-uniform
// masked-row skip. 8 independent fma chains (4 d x 2 halves).
// ---------------------------------------------------------------------------
__global__ __launch_bounds__(256, 4) void score5(
        const __bf16* __restrict__ pm, const __bf16* __restrict__ pdb,
        const float* __restrict__ w_score,
        const unsigned char* __restrict__ mem_mask,
        const unsigned char* __restrict__ dec_mask,
        const unsigned char* __restrict__ dup_mask,
        float* __restrict__ sc) {
    __shared__ __bf16 pdl[4][HDIM];        // 8 KB
    int bid = blockIdx.x;
    int b    = bid & 7;
    int rest = bid >> 3;
    int dg   = rest & 7;
    int mc   = rest >> 3;                  // 0..16
    int t = threadIdx.x, w = t >> 6, l = t & 63;
    int bd0 = b * DEC_LEN + dg * 4;

    {   // cooperative stage: thread t copies 16 bf16 of pd row d = t>>6
        int d  = t >> 6;
        int h0 = (t & 63) * 16;
        const bfv8* src = (const bfv8*)(pdb + (size_t)(bd0 + d) * HDIM + h0);
        bfv8* dst = (bfv8*)&pdl[d][h0];
        dst[0] = src[0];
        dst[1] = src[1];
    }

    f8 w22[2];
    float sumw_l = 0.f;
    #pragma unroll
    for (int half = 0; half < 2; ++half) {
        f8 wv = *(const f8*)(w_score + half * 512 + l * 8);
        #pragma unroll
        for (int j = 0; j < 8; ++j) {
            sumw_l += wv[j];
            w22[half][j] = wv[j] * 2.f;
        }
    }
    #pragma unroll
    for (int off = 32; off; off >>= 1) sumw_l += __shfl_xor(sumw_l, off, 64);
    float sumw_all = sumw_l;

    bool dm[4];
    #pragma unroll
    for (int d = 0; d < 4; ++d) dm[d] = dec_mask[bd0 + d] != 0;
    const unsigned char* dup0 = dup_mask + (size_t)bd0 * M1;

    __syncthreads();

    int mbase = mc * 32 + w * 8;
    for (int i = 0; i < 8; ++i) {
        int m = mbase + i;
        if (m >= M1) break;                // wave-uniform
        bool memm = (m > 0) && (mem_mask[b * MEM_LEN + m - 1] != 0);
        if (memm) {                        // wave-uniform skip (~10% rows)
            if (l == 0) {
                #pragma unroll
                for (int d = 0; d < 4; ++d)
                    sc[(size_t)(bd0 + d) * M1 + m] = NEG_BIG;
            }
            continue;
        }
        const __bf16* pmr = pm + ((size_t)(b * M1 + m)) * HDIM + l * 8;
        bfv8 p0 = *(const bfv8*)(pmr);
        bfv8 p1 = *(const bfv8*)(pmr + 512);
        float ac[4][2] = {};
        #pragma unroll
        for (int d = 0; d < 4; ++d) {
            bfv8 q0 = *(const bfv8*)&pdl[d][l * 8];          // ds_read_b128,
            bfv8 q1 = *(const bfv8*)&pdl[d][512 + l * 8];    // conflict-free
            #pragma unroll
            for (int j = 0; j < 8; ++j) {
                float e0 = EXP2((float)p0[j] + (float)q0[j]);
                ac[d][0] = fmaf(w22[0][j], RCP(e0 + 1.f), ac[d][0]);
                float e1 = EXP2((float)p1[j] + (float)q1[j]);
                ac[d][1] = fmaf(w22[1][j], RCP(e1 + 1.f), ac[d][1]);
            }
        }
        float a0 = ac[0][0] + ac[0][1];
        float a1 = ac[1][0] + ac[1][1];
        float a2 = ac[2][0] + ac[2][1];
        float a3 = ac[3][0] + ac[3][1];
        #pragma unroll
        for (int off = 32; off; off >>= 1) {
            a0 += __shfl_xor(a0, off, 64);
            a1 += __shfl_xor(a1, off, 64);
            a2 += __shfl_xor(a2, off, 64);
            a3 += __shfl_xor(a3, off, 64);
        }
        float s[4];
        s[0] = sumw_all - a0;
        s[1] = sumw_all - a1;
        s[2] = sumw_all - a2;
        s[3] = sumw_all - a3;
        #pragma unroll
        for (int d = 0; d < 4; ++d) {
            bool kill = (!dm[d] && dup0[(size_t)d * M1 + m]);
            s[d] = kill ? NEG_BIG : s[d];
        }
        if (l == 0) {
            #pragma unroll
            for (int d = 0; d < 4; ++d)
                sc[(size_t)(bd0 + d) * M1 + m] = s[d];
        }
    }
}

// ---------------------------------------------------------------------------
// Kernel 4: row-wise log_softmax over 513 entries. One block per (b,d).
// ---------------------------------------------------------------------------
__global__ __launch_bounds__(512) void softmax_k(const float* __restrict__ sc,
                                                 float* __restrict__ out) {
    __shared__ float red[512];
    int bd = blockIdx.x, t = threadIdx.x;
    const float* row = sc + (size_t)bd * M1;
    float v = row[t];
    float v512 = row[512];
    float lm = (t == 0) ? fmaxf(v, v512) : v;
    red[t] = lm;
    __syncthreads();
    for (int s = 256; s > 0; s >>= 1) {
        if (t < s) red[t] = fmaxf(red[t], red[t + s]);
        __syncthreads();
    }
    float mx = red[0];
    __syncthreads();
    float le = __expf(v - mx);             // exp(NEG_BIG - mx) == 0 exactly
    if (t == 0) le += __expf(v512 - mx);
    red[t] = le;
    __syncthreads();
    for (int s = 256; s > 0; s >>= 1) {
        if (t < s) red[t] += red[t + s];
        __syncthreads();
    }
    float lse = mx + __logf(red[0]);
    float* orow = out + (size_t)bd * M1;
    orow[t] = v - lse;
    if (t == 0) orow[512] = v512 - lse;
}

// ---------------------------------------------------------------------------
extern "C" void kernel_launch(void* const* d_in, const int* in_sizes, int n_in,
                              void* d_out, int out_size, void* d_ws, size_t ws_size,
                              hipStream_t stream) {
    const float* mem      = (const float*)d_in[0];
    const float* dec_hid  = (const float*)d_in[1];
    const unsigned char* mem_mask = (const unsigned char*)d_in[2];
    const unsigned char* dec_mask = (const unsigned char*)d_in[3];
    const unsigned char* dup_mask = (const unsigned char*)d_in[4];
    const float* term     = (const float*)d_in[5];
    const float* W_mem    = (const float*)d_in[6];
    const float* b_mem    = (const float*)d_in[7];
    const float* W_dec    = (const float*)d_in[8];
    const float* b_dec    = (const float*)d_in[9];
    const float* w_score  = (const float*)d_in[10];
    // d_in[11] = b_score : unused (log_softmax is shift-invariant)

    float* out = (float*)d_out;
    char* ws = (char*)d_ws;
    __bf16* mfb  = (__bf16*)ws;                              // 4224*512*2  = 4,325,376
    __bf16* decb = mfb + (size_t)AROWS * 512;                //  256*512*2  =   262,144
    __bf16* wmb  = decb + (size_t)256 * 512;                 // 1024*512*2  = 1,048,576
    __bf16* wdb  = wmb + (size_t)1024 * 512;                 // 1024*512*2  = 1,048,576
    __bf16* pmb  = wdb + (size_t)1024 * 512;                 // 4224*1024*2 = 8,650,752
    __bf16* pdb  = pmb + (size_t)AROWS * HDIM;               //  256*1024*2 =   524,288
    float*  sc   = (float*)(pdb + (size_t)256 * HDIM);       //  256*513*4  =   525,312

    convert_all<<<N_CVT / 256, 256, 0, stream>>>(mem, term, dec_hid, W_mem, W_dec,
                                                 mfb, decb, wmb, wdb);
    gemm_pipe<<<1120, 256, 0, stream>>>(mfb, decb, wmb, wdb, b_mem, b_dec, pmb, pdb);
    score5<<<8 * 8 * 17, 256, 0, stream>>>(pmb, pdb, w_score,
                                           mem_mask, dec_mask, dup_mask, sc);
    softmax_k<<<B * DEC_LEN, 512, 0, stream>>>(sc, out);
}

// Round 11
// 52.703 us; speedup vs baseline: 1.8001x; 1.7063x over previous
//
#include <hip/hip_runtime.h>
#include <hip/hip_bf16.h>
#include <math.h>

// Sizes (fixed by the problem)
#define B 8
#define MEM_LEN 512
#define DEC_LEN 32
#define HDIM 1024
#define M1 513
#define PM_ROWS (B * M1)   // 4104
#define AROWS 4224         // 66*64 padded pm rows

// Finite -inf stand-in (exact -inf makes |ref-out| = NaN in the harness check).
#define NEG_BIG (-1e30f)
// 2*log2(e): tanh(x) = 1 - 2*rcp(1 + exp2(C2*x)). W pre-scaled by C2;
// GEMM epilogue stores Em = exp2(C2*pm), Ed = exp2(C2*pd), so the score
// kernel needs only a MUL (Em*Ed) + rcp per element (1 trans, not 2).
#define C2F 2.885390081777927f

#if __has_builtin(__builtin_amdgcn_exp2f)
#define EXP2(x) __builtin_amdgcn_exp2f(x)
#else
#define EXP2(x) exp2f(x)
#endif
#define RCP(x) __builtin_amdgcn_rcpf(x)
#define SCHED_FENCE() __builtin_amdgcn_sched_barrier(0)

typedef __bf16 bfv8 __attribute__((ext_vector_type(8)));
typedef float  f4   __attribute__((ext_vector_type(4)));
typedef float  f8   __attribute__((ext_vector_type(8)));

// ---------------------------------------------------------------------------
// Kernel 1: convert GEMM operands to bf16 (assemble mem_full + zero pad;
// weights pre-scaled by C2). One thread = 8 elements.
// ---------------------------------------------------------------------------
#define N_MF  (AROWS * 512 / 8)         // 270336
#define N_DEC (256 * 512 / 8)           // 16384
#define N_W   (1024 * 512 / 8)          // 65536
#define N_CVT (N_MF + N_DEC + 2 * N_W)  // 417792 = 1632*256

__global__ __launch_bounds__(256) void convert_all(
        const float* __restrict__ mem, const float* __restrict__ term,
        const float* __restrict__ dec_hid,
        const float* __restrict__ W_mem, const float* __restrict__ W_dec,
        __bf16* __restrict__ mfb, __bf16* __restrict__ decb,
        __bf16* __restrict__ wmb, __bf16* __restrict__ wdb) {
    int idx = blockIdx.x * 256 + threadIdx.x;
    float4 v0 = make_float4(0.f, 0.f, 0.f, 0.f), v1 = v0;
    float scale = 1.f;
    __bf16* dst;
    if (idx < N_MF) {
        int row = idx >> 6;          // 64 chunks of 8 per 512-wide row
        int c8  = idx & 63;
        dst = mfb + (size_t)idx * 8;
        if (row < PM_ROWS) {
            int b = row / M1, m = row - b * M1;
            const float* src = (m == 0) ? (term + c8 * 8)
                                        : (mem + ((size_t)(b * MEM_LEN + m - 1)) * 512 + c8 * 8);
            v0 = ((const float4*)src)[0];
            v1 = ((const float4*)src)[1];
        } // else rows >= 4104 stay zero (GEMM pad)
    } else if (idx < N_MF + N_DEC) {
        int j = idx - N_MF;
        dst = decb + (size_t)j * 8;
        v0 = ((const float4*)dec_hid)[j * 2];
        v1 = ((const float4*)dec_hid)[j * 2 + 1];
    } else if (idx < N_MF + N_DEC + N_W) {
        int j = idx - N_MF - N_DEC;
        dst = wmb + (size_t)j * 8;
        v0 = ((const float4*)W_mem)[j * 2];
        v1 = ((const float4*)W_mem)[j * 2 + 1];
        scale = C2F;
    } else {
        int j = idx - N_MF - N_DEC - N_W;
        dst = wdb + (size_t)j * 8;
        v0 = ((const float4*)W_dec)[j * 2];
        v1 = ((const float4*)W_dec)[j * 2 + 1];
        scale = C2F;
    }
    bfv8 o;
    o[0] = (__bf16)(v0.x * scale); o[1] = (__bf16)(v0.y * scale);
    o[2] = (__bf16)(v0.z * scale); o[3] = (__bf16)(v0.w * scale);
    o[4] = (__bf16)(v1.x * scale); o[5] = (__bf16)(v1.y * scale);
    o[6] = (__bf16)(v1.z * scale); o[7] = (__bf16)(v1.w * scale);
    *(bfv8*)dst = o;
}

// ---------------------------------------------------------------------------
// Kernel 2: LDS-staged bf16 MFMA GEMM (m97-style, T3-minimum 2-phase loop).
// R4-R10 diagnosis: direct-from-global fragment loads are SCATTERED (16 rows
// x 1KB stride per wave-load = 32 cache lines per instr) -> TA-serialized at
// ~40us regardless of pipelining. Fix: coalesced global loads (8 lanes read
// 128B contiguous) -> reg -> ds_write with T2 XOR chunk swizzle; fragments
// come from LDS via conflict-free ds_read_b128 (write+read same XOR, rule#21).
// Fully-unrolled kt loop => buffer indices are literals (R6 lesson: runtime
// buf index kills compiler scheduling). One barrier per K-step; gloads for
// step k+1 issued before step k's compute (vmcnt wait lands after MFMAs).
// Epilogue: out = exp2(acc + C2*bias)  (Em / Ed exponential form for score).
// Tile 64x64, BK=64, 4 waves (2x2) of 32x32. LDS 32KB -> ~4 blocks/CU.
// Layouts (HW-verified m89/m91): A/B frag lane l -> row (l&15), k=(l>>4)*8+j;
// C/D: col = l&15, row = (l>>4)*4 + reg.
// ---------------------------------------------------------------------------
__global__ __launch_bounds__(256, 4) void gemm_ls(
        const __bf16* __restrict__ mfb, const __bf16* __restrict__ decb,
        const __bf16* __restrict__ wmb, const __bf16* __restrict__ wdb,
        const float* __restrict__ b_mem, const float* __restrict__ b_dec,
        __bf16* __restrict__ pmb, __bf16* __restrict__ pdb) {
    __shared__ __align__(16) __bf16 Als[2][64 * 64];   // 2 x 8KB
    __shared__ __align__(16) __bf16 Bls[2][64 * 64];   // 2 x 8KB

    int orig = blockIdx.x;                       // 0..1119
    int wg   = (orig & 7) * 140 + (orig >> 3);   // chunked XCD swizzle (8*140)
    int bx   = wg >> 4;                          // 0..69
    int by   = wg & 15;

    bool isMem = bx < 66;
    const __bf16* A  = isMem ? mfb : decb;
    const __bf16* Wb = isMem ? wmb : wdb;
    const float* bsel = isMem ? b_mem : b_dec;
    __bf16* Cout      = isMem ? pmb : pdb;
    int row0 = isMem ? bx * 64 : (bx - 66) * 64;
    int n0b  = by * 64;

    int t = threadIdx.x;
    // staging: thread t owns chunks c0=t, c1=t+256 of the 512 (64 rows x 8)
    // 16B chunks per tile. 8 consecutive threads read 128B contiguous.
    int r0 = t >> 3,          g0 = t & 7;
    int r1 = (t + 256) >> 3,  g1 = t & 7;
    int ds0 = r0 * 128 + ((g0 ^ (r0 & 7)) << 4);   // swizzled byte offsets
    int ds1 = r1 * 128 + ((g1 ^ (r1 & 7)) << 4);
    const __bf16* aSrc0 = A  + (size_t)(row0 + r0) * 512 + g0 * 8;
    const __bf16* aSrc1 = A  + (size_t)(row0 + r1) * 512 + g1 * 8;
    const __bf16* bSrc0 = Wb + (size_t)(n0b + r0) * 512 + g0 * 8;
    const __bf16* bSrc1 = Wb + (size_t)(n0b + r1) * 512 + g1 * 8;

    int w = t >> 6, l = t & 63;
    int m0w = (w >> 1) * 32, n0w = (w & 1) * 32;
    int lr = l & 15, lq = l >> 4;

    f4 acc[2][2] = {};

    // prologue: stage K-tile 0 into buf 0
    {
        bfv8 a0 = *(const bfv8*)(aSrc0);
        bfv8 a1 = *(const bfv8*)(aSrc1);
        bfv8 b0 = *(const bfv8*)(bSrc0);
        bfv8 b1 = *(const bfv8*)(bSrc1);
        *(bfv8*)((char*)&Als[0][0] + ds0) = a0;
        *(bfv8*)((char*)&Als[0][0] + ds1) = a1;
        *(bfv8*)((char*)&Bls[0][0] + ds0) = b0;
        *(bfv8*)((char*)&Bls[0][0] + ds1) = b1;
    }
    __syncthreads();

    #pragma unroll
    for (int kt = 0; kt < 8; ++kt) {
        const int cur = kt & 1;
        bfv8 na0, na1, nb0, nb1;
        if (kt < 7) {                      // issue next-tile loads EARLY
            const int kn = (kt + 1) * 64;
            na0 = *(const bfv8*)(aSrc0 + kn);
            na1 = *(const bfv8*)(aSrc1 + kn);
            nb0 = *(const bfv8*)(bSrc0 + kn);
            nb1 = *(const bfv8*)(bSrc1 + kn);
        }
        SCHED_FENCE();                     // keep load issue above compute
        // fragments: 8 ds_read_b128 (swizzled, conflict-free) then 8 MFMA
        bfv8 aF[2][2], bF[2][2];
        #pragma unroll
        for (int kk = 0; kk < 2; ++kk) {
            int g = kk * 4 + lq;
            #pragma unroll
            for (int i = 0; i < 2; ++i) {
                int rA = m0w + i * 16 + lr;
                aF[kk][i] = *(const bfv8*)((char*)&Als[cur][0] + rA * 128 + ((g ^ (rA & 7)) << 4));
                int rB = n0w + i * 16 + lr;
                bF[kk][i] = *(const bfv8*)((char*)&Bls[cur][0] + rB * 128 + ((g ^ (rB & 7)) << 4));
            }
        }
        #pragma unroll
        for (int kk = 0; kk < 2; ++kk) {
            acc[0][0] = __builtin_amdgcn_mfma_f32_16x16x32_bf16(aF[kk][0], bF[kk][0], acc[0][0], 0, 0, 0);
            acc[0][1] = __builtin_amdgcn_mfma_f32_16x16x32_bf16(aF[kk][0], bF[kk][1], acc[0][1], 0, 0, 0);
            acc[1][0] = __builtin_amdgcn_mfma_f32_16x16x32_bf16(aF[kk][1], bF[kk][0], acc[1][0], 0, 0, 0);
            acc[1][1] = __builtin_amdgcn_mfma_f32_16x16x32_bf16(aF[kk][1], bF[kk][1], acc[1][1], 0, 0, 0);
        }
        if (kt < 7) {                      // write next tile to other buffer
            const int nxt = cur ^ 1;
            *(bfv8*)((char*)&Als[nxt][0] + ds0) = na0;
            *(bfv8*)((char*)&Als[nxt][0] + ds1) = na1;
            *(bfv8*)((char*)&Bls[nxt][0] + ds0) = nb0;
            *(bfv8*)((char*)&Bls[nxt][0] + ds1) = nb1;
        }
        __syncthreads();
    }

    // epilogue: Em/Ed = exp2(acc + C2*bias), bf16 store
    int crow = lq * 4;
    int ccol = lr;
    #pragma unroll
    for (int j = 0; j < 2; ++j) {
        int col = n0b + n0w + j * 16 + ccol;
        float bv = bsel[col] * C2F;
        #pragma unroll
        for (int i = 0; i < 2; ++i) {
            #pragma unroll
            for (int r = 0; r < 4; ++r) {
                int row = row0 + m0w + i * 16 + crow + r;
                Cout[(size_t)row * HDIM + col] = (__bf16)EXP2(acc[i][j][r] + bv);
            }
        }
    }
}

// ---------------------------------------------------------------------------
// Kernel 3: score[b,d,m] = SumW - sum_h 2*w[h]*rcp(1 + Em*Ed)
// Em = exp2(C2*pm), Ed = exp2(C2*pd) precomputed in the GEMM epilogue ->
// inner loop is mul+add+rcp+fma: ONE transcendental per element (was two).
// Ed tile staged in LDS (8KB, allocator-independent — R9 lesson). Grid:
// b(8) x dgroup(8, 4 d) x mchunk(17); b = bid&7 -> XCD. 4 waves x 8 rows.
// ---------------------------------------------------------------------------
__global__ __launch_bounds__(256, 4) void score6(
        const __bf16* __restrict__ pm, const __bf16* __restrict__ pdb,
        const float* __restrict__ w_score,
        const unsigned char* __restrict__ mem_mask,
        const unsigned char* __restrict__ dec_mask,
        const unsigned char* __restrict__ dup_mask,
        float* __restrict__ sc) {
    __shared__ __bf16 pdl[4][HDIM];        // 8 KB (Ed, bf16)
    int bid = blockIdx.x;
    int b    = bid & 7;
    int rest = bid >> 3;
    int dg   = rest & 7;
    int mc   = rest >> 3;                  // 0..16
    int t = threadIdx.x, w = t >> 6, l = t & 63;
    int bd0 = b * DEC_LEN + dg * 4;

    {   // cooperative stage: thread t copies 16 bf16 of Ed row d = t>>6
        int d  = t >> 6;
        int h0 = (t & 63) * 16;
        const bfv8* src = (const bfv8*)(pdb + (size_t)(bd0 + d) * HDIM + h0);
        bfv8* dst = (bfv8*)&pdl[d][h0];
        dst[0] = src[0];
        dst[1] = src[1];
    }

    f8 w22[2];
    float sumw_l = 0.f;
    #pragma unroll
    for (int half = 0; half < 2; ++half) {
        f8 wv = *(const f8*)(w_score + half * 512 + l * 8);
        #pragma unroll
        for (int j = 0; j < 8; ++j) {
            sumw_l += wv[j];
            w22[half][j] = wv[j] * 2.f;
        }
    }
    #pragma unroll
    for (int off = 32; off; off >>= 1) sumw_l += __shfl_xor(sumw_l, off, 64);
    float sumw_all = sumw_l;

    bool dm[4];
    #pragma unroll
    for (int d = 0; d < 4; ++d) dm[d] = dec_mask[bd0 + d] != 0;
    const unsigned char* dup0 = dup_mask + (size_t)bd0 * M1;

    __syncthreads();

    int mbase = mc * 32 + w * 8;
    for (int i = 0; i < 8; ++i) {
        int m = mbase + i;
        if (m >= M1) break;                // wave-uniform
        bool memm = (m > 0) && (mem_mask[b * MEM_LEN + m - 1] != 0);
        if (memm) {                        // wave-uniform skip (~10% rows)
            if (l == 0) {
                #pragma unroll
                for (int d = 0; d < 4; ++d)
                    sc[(size_t)(bd0 + d) * M1 + m] = NEG_BIG;
            }
            continue;
        }
        const __bf16* pmr = pm + ((size_t)(b * M1 + m)) * HDIM + l * 8;
        bfv8 p0 = *(const bfv8*)(pmr);
        bfv8 p1 = *(const bfv8*)(pmr + 512);
        float ac[4][2] = {};
        #pragma unroll
        for (int d = 0; d < 4; ++d) {
            bfv8 q0 = *(const bfv8*)&pdl[d][l * 8];          // ds_read_b128
            bfv8 q1 = *(const bfv8*)&pdl[d][512 + l * 8];
            #pragma unroll
            for (int j = 0; j < 8; ++j) {
                float e0 = (float)p0[j] * (float)q0[j];      // Em*Ed
                ac[d][0] = fmaf(w22[0][j], RCP(e0 + 1.f), ac[d][0]);
                float e1 = (float)p1[j] * (float)q1[j];
                ac[d][1] = fmaf(w22[1][j], RCP(e1 + 1.f), ac[d][1]);
            }
        }
        float a0 = ac[0][0] + ac[0][1];
        float a1 = ac[1][0] + ac[1][1];
        float a2 = ac[2][0] + ac[2][1];
        float a3 = ac[3][0] + ac[3][1];
        #pragma unroll
        for (int off = 32; off; off >>= 1) {
            a0 += __shfl_xor(a0, off, 64);
            a1 += __shfl_xor(a1, off, 64);
            a2 += __shfl_xor(a2, off, 64);
            a3 += __shfl_xor(a3, off, 64);
        }
        float s[4];
        s[0] = sumw_all - a0;
        s[1] = sumw_all - a1;
        s[2] = sumw_all - a2;
        s[3] = sumw_all - a3;
        #pragma unroll
        for (int d = 0; d < 4; ++d) {
            bool kill = (!dm[d] && dup0[(size_t)d * M1 + m]);
            s[d] = kill ? NEG_BIG : s[d];
        }
        if (l == 0) {
            #pragma unroll
            for (int d = 0; d < 4; ++d)
                sc[(size_t)(bd0 + d) * M1 + m] = s[d];
        }
    }
}

// ---------------------------------------------------------------------------
// Kernel 4: row-wise log_softmax over 513 entries. One block per (b,d).
// ---------------------------------------------------------------------------
__global__ __launch_bounds__(512) void softmax_k(const float* __restrict__ sc,
                                                 float* __restrict__ out) {
    __shared__ float red[512];
    int bd = blockIdx.x, t = threadIdx.x;
    const float* row = sc + (size_t)bd * M1;
    float v = row[t];
    float v512 = row[512];
    float lm = (t == 0) ? fmaxf(v, v512) : v;
    red[t] = lm;
    __syncthreads();
    for (int s = 256; s > 0; s >>= 1) {
        if (t < s) red[t] = fmaxf(red[t], red[t + s]);
        __syncthreads();
    }
    float mx = red[0];
    __syncthreads();
    float le = __expf(v - mx);             // exp(NEG_BIG - mx) == 0 exactly
    if (t == 0) le += __expf(v512 - mx);
    red[t] = le;
    __syncthreads();
    for (int s = 256; s > 0; s >>= 1) {
        if (t < s) red[t] += red[t + s];
        __syncthreads();
    }
    float lse = mx + __logf(red[0]);
    float* orow = out + (size_t)bd * M1;
    orow[t] = v - lse;
    if (t == 0) orow[512] = v512 - lse;
}

// ---------------------------------------------------------------------------
extern "C" void kernel_launch(void* const* d_in, const int* in_sizes, int n_in,
                              void* d_out, int out_size, void* d_ws, size_t ws_size,
                              hipStream_t stream) {
    const float* mem      = (const float*)d_in[0];
    const float* dec_hid  = (const float*)d_in[1];
    const unsigned char* mem_mask = (const unsigned char*)d_in[2];
    const unsigned char* dec_mask = (const unsigned char*)d_in[3];
    const unsigned char* dup_mask = (const unsigned char*)d_in[4];
    const float* term     = (const float*)d_in[5];
    const float* W_mem    = (const float*)d_in[6];
    const float* b_mem    = (const float*)d_in[7];
    const float* W_dec    = (const float*)d_in[8];
    const float* b_dec    = (const float*)d_in[9];
    const float* w_score  = (const float*)d_in[10];
    // d_in[11] = b_score : unused (log_softmax is shift-invariant)

    float* out = (float*)d_out;
    char* ws = (char*)d_ws;
    __bf16* mfb  = (__bf16*)ws;                              // 4224*512*2  = 4,325,376
    __bf16* decb = mfb + (size_t)AROWS * 512;                //  256*512*2  =   262,144
    __bf16* wmb  = decb + (size_t)256 * 512;                 // 1024*512*2  = 1,048,576
    __bf16* wdb  = wmb + (size_t)1024 * 512;                 // 1024*512*2  = 1,048,576
    __bf16* pmb  = wdb + (size_t)1024 * 512;                 // 4224*1024*2 = 8,650,752
    __bf16* pdb  = pmb + (size_t)AROWS * HDIM;               //  256*1024*2 =   524,288
    float*  sc   = (float*)(pdb + (size_t)256 * HDIM);       //  256*513*4  =   525,312

    convert_all<<<N_CVT / 256, 256, 0, stream>>>(mem, term, dec_hid, W_mem, W_dec,
                                                 mfb, decb, wmb, wdb);
    gemm_ls<<<1120, 256, 0, stream>>>(mfb, decb, wmb, wdb, b_mem, b_dec, pmb, pdb);
    score6<<<8 * 8 * 17, 256, 0, stream>>>(pmb, pdb, w_score,
                                           mem_mask, dec_mask, dup_mask, sc);
    softmax_k<<<B * DEC_LEN, 512, 0, stream>>>(sc, out);
}